// Round 7
// baseline (221.138 us; speedup 1.0000x reference)
//
#include <hip/hip_runtime.h>
#include <hip/hip_fp16.h>

#define IN_F 128
#define OUT_F 32
#define R_NODES 256          // dst nodes per bucket (8 bits)
#define RSHIFT 8
#define RMASK 255
#define OVF_CAP 4096
#define EPB 8192             // edges per build sub-block
#define MAXNB 512            // max bins => n_nodes <= 131072
#define MAXBBL 256           // max build blocks => n_edges <= 2.09M
#define C_D 40               // dst chunk cap: P(Poisson(21)>40) ~ 5e-5 per chunk
#define SRT_CAP 6144         // per-bucket sorted-src LDS cap (mean 4092)

// ---------------------------------------------------------------------------
// ROUND 7. R6 null (2x back-half threads = -1.9us) -> back half not wave-
// starved. Re-read of R2->R3: removing 1.6M fabric out_cnt atomics saved
// only ~5us -> fabric atomics are CHEAP -> the whole out-degree machinery
// (phase S, bkt2, scale_tmp's scan+hist+12.8MB tmp RMW) is removable:
//  - build: per edge {1 LDS cursor atomic + 1 bkt store + 1 fabric atomic}
//  - scale_tmp DELETED; tiny mkscale builds scl[node]=rsqrt(outdeg) (400KB)
//  - sortgather multiplies per-edge by scl[src] (L2 broadcast load, fp32 FMA)
// Attribution: total delta tells us scale_tmp's true cost; residual pool is
// ~pure sortgather. Falsifier: total>=175 => scale_tmp was free => R8 gather
// rebuild.
// ---------------------------------------------------------------------------
struct BuildSmem { int dcur[MAXNB]; };                   // 2 KB
struct LinSmem { float w[IN_F * OUT_F]; };               // 16 KB
union MegaSmem { BuildSmem b; LinSmem l; };

__global__ __launch_bounds__(512) void mega_kernel(
    const int* __restrict__ src, const int* __restrict__ dst,
    const float* __restrict__ feat, const float* __restrict__ weight,
    int* __restrict__ out_cnt, int* __restrict__ in_cnt,
    unsigned* __restrict__ bkt, unsigned short* __restrict__ cnts_d,
    int* __restrict__ ovf, int* __restrict__ ovf_cnt,
    __half* __restrict__ tmp, int n_edges, int n_nodes,
    int n_bbl, int n_lbl) {

    __shared__ MegaSmem sm;
    int tid = threadIdx.x;
    int bid = blockIdx.x;

    // interleave: every 3rd block is build (n_lbl ~= 2*n_bbl)
    int t = bid / 3, r = bid - 3 * t;
    bool is_build = (r == 0) && (t < n_bbl);
    int sub;
    if (is_build) sub = t;
    else {
        sub = bid - min(t + (r ? 1 : 0), n_bbl);
        if (sub >= n_lbl) return;
    }

    if (is_build) {
        int e0 = sub * EPB;
        int ecnt = min(EPB, n_edges - e0);
        int sD = n_bbl * C_D;            // u32 stride per dst bucket

        for (int i = tid; i < MAXNB; i += 512) sm.b.dcur[i] = 0;
        __syncthreads();

        int k4 = ecnt >> 2;
        const int4* src4 = (const int4*)(src + e0);
        const int4* dst4 = (const int4*)(dst + e0);

#define EDGE(ss, dd) {                                                        \
            int bin = (dd) >> RSHIFT;                                         \
            int idx = atomicAdd(&sm.b.dcur[bin], 1);                          \
            if (idx < C_D) {                                                  \
                bkt[(size_t)bin * sD + sub * C_D + idx] =                     \
                    ((unsigned)(ss) << RSHIFT) | (unsigned)((dd) & RMASK);    \
            } else {                                                          \
                atomicAdd(&in_cnt[dd], 1);                                    \
                int o = atomicAdd(ovf_cnt, 1);                                \
                if (o < OVF_CAP) { ovf[2 * o] = (ss); ovf[2 * o + 1] = (dd); }\
            }                                                                 \
            atomicAdd(&out_cnt[ss], 1);                                       \
        }

        for (int k = tid; k < k4; k += 512) {
            int4 s4 = src4[k];
            int4 d4 = dst4[k];
            EDGE(s4.x, d4.x)
            EDGE(s4.y, d4.y)
            EDGE(s4.z, d4.z)
            EDGE(s4.w, d4.w)
        }
        for (int k = (k4 << 2) + tid; k < ecnt; k += 512) {
            int s = src[e0 + k], d = dst[e0 + k];
            EDGE(s, d)
        }
#undef EDGE
        __syncthreads();

        // publish exact per-(bin,block) counts
        for (int bin = tid; bin < MAXNB; bin += 512) {
            cnts_d[bin * MAXBBL + sub] = (unsigned short)min(sm.b.dcur[bin], C_D);
        }
    } else {
        // ===== linear: tmp(fp16) = feat @ W, UNSCALED (256 rows/block) =====
        for (int i = tid; i < IN_F * OUT_F / 4; i += 512)
            ((float4*)sm.l.w)[i] = ((const float4*)weight)[i];
        __syncthreads();

        int q  = tid >> 3;                  // 0..63 row-quads
        int cg = tid & 7;                   // col group of 4
        int row0 = sub * 256 + q * 4;
        if (row0 >= n_nodes) return;
        int rmax = n_nodes - row0;
        if (rmax > 4) rmax = 4;

        const float4* feat4 = (const float4*)feat;
        float4 acc[4];
#pragma unroll
        for (int rr = 0; rr < 4; ++rr) acc[rr] = make_float4(0.f, 0.f, 0.f, 0.f);

        for (int k4i = 0; k4i < IN_F / 4; ++k4i) {
            float4 wv0 = *(const float4*)&sm.l.w[(4 * k4i + 0) * OUT_F + 4 * cg];
            float4 wv1 = *(const float4*)&sm.l.w[(4 * k4i + 1) * OUT_F + 4 * cg];
            float4 wv2 = *(const float4*)&sm.l.w[(4 * k4i + 2) * OUT_F + 4 * cg];
            float4 wv3 = *(const float4*)&sm.l.w[(4 * k4i + 3) * OUT_F + 4 * cg];
#pragma unroll
            for (int rr = 0; rr < 4; ++rr) {
                int r2 = (rr < rmax) ? rr : 0;
                float4 f = feat4[(size_t)(row0 + r2) * (IN_F / 4) + k4i];
                acc[rr].x += f.x * wv0.x + f.y * wv1.x + f.z * wv2.x + f.w * wv3.x;
                acc[rr].y += f.x * wv0.y + f.y * wv1.y + f.z * wv2.y + f.w * wv3.y;
                acc[rr].z += f.x * wv0.z + f.y * wv1.z + f.z * wv2.z + f.w * wv3.z;
                acc[rr].w += f.x * wv0.w + f.y * wv1.w + f.z * wv2.w + f.w * wv3.w;
            }
        }

#pragma unroll
        for (int rr = 0; rr < 4; ++rr) {
            if (rr < rmax) {
                union { __half h[4]; uint2 u; } pk;
                pk.h[0] = __float2half(acc[rr].x);
                pk.h[1] = __float2half(acc[rr].y);
                pk.h[2] = __float2half(acc[rr].z);
                pk.h[3] = __float2half(acc[rr].w);
                *(uint2*)&tmp[(size_t)(row0 + rr) * OUT_F + 4 * cg] = pk.u;
            }
        }
    }
}

// ---------------------------------------------------------------------------
// mkscale: scl[node] = rsqrt(max(out_deg,1)). 400KB table, L2-resident for
// the gather's broadcast loads.
// ---------------------------------------------------------------------------
__global__ __launch_bounds__(256) void mkscale(const int* __restrict__ out_cnt,
                                               float* __restrict__ scl, int n) {
    int i = blockIdx.x * 256 + threadIdx.x;
    if (i < n) scl[i] = rsqrtf(fmaxf((float)out_cnt[i], 1.0f));
}

// ---------------------------------------------------------------------------
// sortgather: one 1024-thr block per 256-node dst bucket. Two grid scans
// (hist, reorder) with count validity, then 8-lane x uint2 gather with
// per-edge src scale: sum_j scl[s_j] * tmp[s_j] (fp32 FMA).
// ---------------------------------------------------------------------------
__global__ __launch_bounds__(1024) void sortgather_kernel(
    const unsigned* __restrict__ bkt,
    const unsigned short* __restrict__ cnts_d,
    const int* __restrict__ in_cnt, const float* __restrict__ scl,
    const int* __restrict__ ovf, const int* __restrict__ ovf_cnt,
    const __half* __restrict__ tmp, float* __restrict__ out,
    int n_nodes, int n_bbl) {

    __shared__ unsigned srt[SRT_CAP];       // 24 KB (src ids, node-sorted)
    __shared__ unsigned short cnt[MAXBBL];
    __shared__ int hist[R_NODES];
    __shared__ int base[R_NODES];
    __shared__ int start[R_NODES];

    int b = blockIdx.x, tid = threadIdx.x;

    if (tid < R_NODES) hist[tid] = 0;
    for (int i = tid; i < n_bbl; i += 1024) cnt[i] = cnts_d[b * MAXBBL + i];
    __syncthreads();

    int sD = n_bbl * C_D;
    const uint4* g4 = (const uint4*)(bkt + (size_t)b * sD);
    int n4 = sD >> 2;                       // 4 u32 entries per uint4 (4|C_D)

    for (int i = tid; i < n4; i += 1024) {
        int e0 = i << 2;
        int c = e0 / C_D;                   // const-div -> magic mul
        int w = e0 - c * C_D;
        int cc = cnt[c];
        if (w >= cc) continue;
        uint4 v = g4[i];
        atomicAdd(&hist[v.x & RMASK], 1);
        if (w + 1 < cc) atomicAdd(&hist[v.y & RMASK], 1);
        if (w + 2 < cc) atomicAdd(&hist[v.z & RMASK], 1);
        if (w + 3 < cc) atomicAdd(&hist[v.w & RMASK], 1);
    }
    __syncthreads();

    if (tid < 64) {                      // scan 256 bins, 4/lane
        int a0 = hist[4 * tid], a1 = hist[4 * tid + 1];
        int a2 = hist[4 * tid + 2], a3 = hist[4 * tid + 3];
        int s = a0 + a1 + a2 + a3;
        int sc = s;
        for (int off = 1; off < 64; off <<= 1) {
            int v = __shfl_up(sc, off, 64);
            if (tid >= off) sc += v;
        }
        int excl = sc - s;
        base[4 * tid]     = excl;
        base[4 * tid + 1] = excl + a0;
        base[4 * tid + 2] = excl + a0 + a1;
        base[4 * tid + 3] = excl + a0 + a1 + a2;
    }
    __syncthreads();
    if (tid < R_NODES) start[tid] = base[tid];
    __syncthreads();

    for (int i = tid; i < n4; i += 1024) {
        int e0 = i << 2;
        int c = e0 / C_D;
        int w = e0 - c * C_D;
        int cc = cnt[c];
        if (w >= cc) continue;
        uint4 v = g4[i];
        int p;
        p = atomicAdd(&base[v.x & RMASK], 1);
        if (p < SRT_CAP) srt[p] = v.x >> RSHIFT;
        if (w + 1 < cc) { p = atomicAdd(&base[v.y & RMASK], 1);
                          if (p < SRT_CAP) srt[p] = v.y >> RSHIFT; }
        if (w + 2 < cc) { p = atomicAdd(&base[v.z & RMASK], 1);
                          if (p < SRT_CAP) srt[p] = v.z >> RSHIFT; }
        if (w + 3 < cc) { p = atomicAdd(&base[v.w & RMASK], 1);
                          if (p < SRT_CAP) srt[p] = v.w >> RSHIFT; }
    }
    __syncthreads();

    int g = tid >> 3;                    // group 0..127
    int c = tid & 7;                     // uint2 (4-half) column group
    int n0 = b * R_NODES;
    int novf = min(*ovf_cnt, OVF_CAP);

    for (int ln = g; ln < R_NODES; ln += 128) {
        int node = n0 + ln;
        if (node >= n_nodes) continue;
        int cntn = hist[ln];
        int st   = start[ln];

        float a0 = 0.f, a1 = 0.f, a2 = 0.f, a3 = 0.f;
        float b0 = 0.f, b1 = 0.f, b2 = 0.f, b3 = 0.f;
        int j = 0;
        for (; j + 8 <= cntn; j += 8) {
            int s0 = (int)srt[st + j + 0], s1 = (int)srt[st + j + 1];
            int s2 = (int)srt[st + j + 2], s3 = (int)srt[st + j + 3];
            int s4 = (int)srt[st + j + 4], s5 = (int)srt[st + j + 5];
            int s6 = (int)srt[st + j + 6], s7 = (int)srt[st + j + 7];
            float w0 = scl[s0], w1 = scl[s1], w2 = scl[s2], w3 = scl[s3];
            float w4 = scl[s4], w5 = scl[s5], w6 = scl[s6], w7 = scl[s7];
            uint2 v0 = *(const uint2*)(tmp + (size_t)s0 * OUT_F + 4 * c);
            uint2 v1 = *(const uint2*)(tmp + (size_t)s1 * OUT_F + 4 * c);
            uint2 v2 = *(const uint2*)(tmp + (size_t)s2 * OUT_F + 4 * c);
            uint2 v3 = *(const uint2*)(tmp + (size_t)s3 * OUT_F + 4 * c);
            uint2 v4 = *(const uint2*)(tmp + (size_t)s4 * OUT_F + 4 * c);
            uint2 v5 = *(const uint2*)(tmp + (size_t)s5 * OUT_F + 4 * c);
            uint2 v6 = *(const uint2*)(tmp + (size_t)s6 * OUT_F + 4 * c);
            uint2 v7 = *(const uint2*)(tmp + (size_t)s7 * OUT_F + 4 * c);
            const __half2* h;
            float2 f;
            h = (const __half2*)&v0;
            f = __half22float2(h[0]); a0 += w0 * f.x; a1 += w0 * f.y;
            f = __half22float2(h[1]); a2 += w0 * f.x; a3 += w0 * f.y;
            h = (const __half2*)&v1;
            f = __half22float2(h[0]); b0 += w1 * f.x; b1 += w1 * f.y;
            f = __half22float2(h[1]); b2 += w1 * f.x; b3 += w1 * f.y;
            h = (const __half2*)&v2;
            f = __half22float2(h[0]); a0 += w2 * f.x; a1 += w2 * f.y;
            f = __half22float2(h[1]); a2 += w2 * f.x; a3 += w2 * f.y;
            h = (const __half2*)&v3;
            f = __half22float2(h[0]); b0 += w3 * f.x; b1 += w3 * f.y;
            f = __half22float2(h[1]); b2 += w3 * f.x; b3 += w3 * f.y;
            h = (const __half2*)&v4;
            f = __half22float2(h[0]); a0 += w4 * f.x; a1 += w4 * f.y;
            f = __half22float2(h[1]); a2 += w4 * f.x; a3 += w4 * f.y;
            h = (const __half2*)&v5;
            f = __half22float2(h[0]); b0 += w5 * f.x; b1 += w5 * f.y;
            f = __half22float2(h[1]); b2 += w5 * f.x; b3 += w5 * f.y;
            h = (const __half2*)&v6;
            f = __half22float2(h[0]); a0 += w6 * f.x; a1 += w6 * f.y;
            f = __half22float2(h[1]); a2 += w6 * f.x; a3 += w6 * f.y;
            h = (const __half2*)&v7;
            f = __half22float2(h[0]); b0 += w7 * f.x; b1 += w7 * f.y;
            f = __half22float2(h[1]); b2 += w7 * f.x; b3 += w7 * f.y;
        }
        for (; j < cntn; ++j) {
            int s = (int)srt[st + j];
            float ws = scl[s];
            uint2 v = *(const uint2*)(tmp + (size_t)s * OUT_F + 4 * c);
            const __half2* h = (const __half2*)&v;
            float2 f;
            if (j & 1) {
                f = __half22float2(h[0]); b0 += ws * f.x; b1 += ws * f.y;
                f = __half22float2(h[1]); b2 += ws * f.x; b3 += ws * f.y;
            } else {
                f = __half22float2(h[0]); a0 += ws * f.x; a1 += ws * f.y;
                f = __half22float2(h[1]); a2 += ws * f.x; a3 += ws * f.y;
            }
        }
        for (int e2 = 0; e2 < novf; ++e2) {        // ~always empty
            if (ovf[2 * e2 + 1] == node) {
                int s = ovf[2 * e2];
                float ws = scl[s];
                uint2 v = *(const uint2*)(tmp + (size_t)s * OUT_F + 4 * c);
                const __half2* h = (const __half2*)&v;
                float2 f;
                f = __half22float2(h[0]); a0 += ws * f.x; a1 += ws * f.y;
                f = __half22float2(h[1]); a2 += ws * f.x; a3 += ws * f.y;
            }
        }

        float dg = (float)(cntn + in_cnt[node]);
        float sc = rsqrtf(fmaxf(dg, 1.0f));
        float4 o = make_float4((a0 + b0) * sc, (a1 + b1) * sc,
                               (a2 + b2) * sc, (a3 + b3) * sc);
        *(float4*)(out + (size_t)node * OUT_F + 4 * c) = o;
    }
}

// ---------------------------------------------------------------------------
// Fallback path (ws too small): degree + scaled-linear + atomic scatter.
// ---------------------------------------------------------------------------
__global__ void degree_kernel(const int* __restrict__ src, const int* __restrict__ dst,
                              int* __restrict__ out_cnt, int* __restrict__ in_cnt,
                              int n_edges) {
    int i = blockIdx.x * blockDim.x + threadIdx.x;
    if (i < n_edges) {
        atomicAdd(&out_cnt[src[i]], 1);
        atomicAdd(&in_cnt[dst[i]], 1);
    }
}

__global__ __launch_bounds__(256) void linear_fb(const float* __restrict__ feat,
                                                 const float* __restrict__ weight,
                                                 const int* __restrict__ out_cnt,
                                                 __half* __restrict__ tmp, int n_nodes) {
    __shared__ float w[IN_F * OUT_F];
    {
        const float4* wg = (const float4*)weight;
        float4* wsh = (float4*)w;
        for (int i = threadIdx.x; i < IN_F * OUT_F / 4; i += 256) wsh[i] = wg[i];
    }
    __syncthreads();
    int q  = threadIdx.x >> 3;
    int cg = threadIdx.x & 7;
    int row0 = blockIdx.x * 128 + q * 4;
    if (row0 >= n_nodes) return;
    int rmax = n_nodes - row0;
    if (rmax > 4) rmax = 4;
    const float4* feat4 = (const float4*)feat;
    float4 acc[4];
#pragma unroll
    for (int r = 0; r < 4; ++r) acc[r] = make_float4(0.f, 0.f, 0.f, 0.f);
    for (int k4 = 0; k4 < IN_F / 4; ++k4) {
        float4 wv0 = *(const float4*)&w[(4 * k4 + 0) * OUT_F + 4 * cg];
        float4 wv1 = *(const float4*)&w[(4 * k4 + 1) * OUT_F + 4 * cg];
        float4 wv2 = *(const float4*)&w[(4 * k4 + 2) * OUT_F + 4 * cg];
        float4 wv3 = *(const float4*)&w[(4 * k4 + 3) * OUT_F + 4 * cg];
#pragma unroll
        for (int r = 0; r < 4; ++r) {
            int rr = (r < rmax) ? r : 0;
            float4 f = feat4[(size_t)(row0 + rr) * (IN_F / 4) + k4];
            acc[r].x += f.x * wv0.x + f.y * wv1.x + f.z * wv2.x + f.w * wv3.x;
            acc[r].y += f.x * wv0.y + f.y * wv1.y + f.z * wv2.y + f.w * wv3.y;
            acc[r].z += f.x * wv0.z + f.y * wv1.z + f.z * wv2.z + f.w * wv3.z;
            acc[r].w += f.x * wv0.w + f.y * wv1.w + f.z * wv2.w + f.w * wv3.w;
        }
    }
#pragma unroll
    for (int r = 0; r < 4; ++r) {
        if (r < rmax) {
            float sc = rsqrtf(fmaxf((float)out_cnt[row0 + r], 1.0f));
            union { __half h[4]; uint2 u; } pk;
            pk.h[0] = __float2half(acc[r].x * sc);
            pk.h[1] = __float2half(acc[r].y * sc);
            pk.h[2] = __float2half(acc[r].z * sc);
            pk.h[3] = __float2half(acc[r].w * sc);
            *(uint2*)&tmp[(size_t)(row0 + r) * OUT_F + 4 * cg] = pk.u;
        }
    }
}

__global__ void scatter_kernel(const int* __restrict__ src, const int* __restrict__ dst,
                               const __half* __restrict__ tmp, float* __restrict__ out,
                               int n_edges) {
    long long t = (long long)blockIdx.x * blockDim.x + threadIdx.x;
    int e = (int)(t >> 5);
    int c = (int)(t & (OUT_F - 1));
    if (e < n_edges) {
        atomicAdd(&out[(size_t)dst[e] * OUT_F + c],
                  __half2float(tmp[(size_t)src[e] * OUT_F + c]));
    }
}

__global__ void finalize_kernel(float* __restrict__ out, const int* __restrict__ in_cnt,
                                int n_total) {
    int t = blockIdx.x * blockDim.x + threadIdx.x;
    if (t < n_total) {
        out[t] *= rsqrtf(fmaxf((float)in_cnt[t >> 5], 1.0f));
    }
}

extern "C" void kernel_launch(void* const* d_in, const int* in_sizes, int n_in,
                              void* d_out, int out_size, void* d_ws, size_t ws_size,
                              hipStream_t stream) {
    const float* feat   = (const float*)d_in[0];
    const int*   src    = (const int*)d_in[1];
    const int*   dst    = (const int*)d_in[2];
    const float* weight = (const float*)d_in[3];
    float*       out    = (float*)d_out;

    int n_nodes = in_sizes[0] / IN_F;   // 100000
    int n_edges = in_sizes[1];          // 1600000
    int n_buckets = (n_nodes + R_NODES - 1) / R_NODES;  // 391
    int n_bbl = (n_edges + EPB - 1) / EPB;              // 196
    int n_lbl = (n_nodes + 255) / 256;                  // 391

    // ws layout: [out_cnt n][in_cnt n][ovf_cnt 8][ovf 2*CAP]
    //            [cnts_d MAXNB*MAXBBL u16][scl n f32][bkt nb x n_bbl*C_D u32]
    //            [tmp fp16 n*32 (16B aligned)]
    int*      out_cnt = (int*)d_ws;
    int*      in_cnt  = out_cnt + n_nodes;
    int*      ovf_cnt = in_cnt + n_nodes;
    int*      ovf     = ovf_cnt + 8;
    unsigned short* cnts_d = (unsigned short*)(ovf + 2 * OVF_CAP);
    float*    scl     = (float*)(cnts_d + (size_t)MAXNB * MAXBBL);
    char*     bkt_raw = (char*)(scl + n_nodes);
    unsigned* bkt     = (unsigned*)(((uintptr_t)bkt_raw + 15) & ~(uintptr_t)15);
    int sD = n_bbl * C_D;
    char*     tmp_raw = (char*)(bkt + (size_t)n_buckets * sD);
    __half*   tmp     = (__half*)(((uintptr_t)tmp_raw + 15) & ~(uintptr_t)15);
    size_t    needed  = (char*)(tmp + (size_t)n_nodes * OUT_F) - (char*)d_ws;

    if (ws_size >= needed && n_buckets <= MAXNB && n_bbl <= MAXBBL) {
        hipMemsetAsync(out_cnt, 0, ((size_t)2 * n_nodes + 8) * sizeof(int), stream);
        mega_kernel<<<n_bbl + n_lbl, 512, 0, stream>>>(
            src, dst, feat, weight, out_cnt, in_cnt, bkt,
            cnts_d, ovf, ovf_cnt, tmp, n_edges, n_nodes, n_bbl, n_lbl);
        mkscale<<<(n_nodes + 255) / 256, 256, 0, stream>>>(out_cnt, scl, n_nodes);
        sortgather_kernel<<<n_buckets, 1024, 0, stream>>>(
            bkt, cnts_d, in_cnt, scl, ovf, ovf_cnt, tmp, out, n_nodes, n_bbl);
    } else {
        // fallback: atomic scatter
        __half* tmp_fb = (__half*)(ovf + 2 * OVF_CAP);
        hipMemsetAsync(out_cnt, 0, ((size_t)2 * n_nodes + 8) * sizeof(int), stream);
        hipMemsetAsync(d_out, 0, (size_t)out_size * sizeof(float), stream);
        degree_kernel<<<(n_edges + 255) / 256, 256, 0, stream>>>(src, dst, out_cnt, in_cnt, n_edges);
        linear_fb<<<(n_nodes + 127) / 128, 256, 0, stream>>>(feat, weight, out_cnt, tmp_fb, n_nodes);
        long long st = (long long)n_edges * OUT_F;
        scatter_kernel<<<(int)((st + 255) / 256), 256, 0, stream>>>(src, dst, tmp_fb, out, n_edges);
        finalize_kernel<<<(n_nodes * OUT_F + 255) / 256, 256, 0, stream>>>(out, in_cnt, n_nodes * OUT_F);
    }
}

// Round 8
// 188.364 us; speedup vs baseline: 1.1740x; 1.1740x over previous
//
#include <hip/hip_runtime.h>
#include <hip/hip_fp16.h>

#define IN_F 128
#define OUT_F 32
#define R_NODES 256          // dst nodes per bucket (8 bits)
#define RSHIFT 8
#define RMASK 255
#define OVF_CAP 4096
#define EPB 8192             // edges per build sub-block
#define MAXNB 512            // max bins => n_nodes <= 131072
#define MAXBBL 256           // max build blocks => n_edges <= 2.09M
#define C_D 40               // dst chunk cap: P(Poisson(21)>40) ~ 5e-5 per chunk
#define C_S 32               // src chunk cap: overflow -> fabric atomic (rare)
#define SRT_CAP 6144         // per-bucket edge cap (mean 4092, ~32 sigma)

// ---------------------------------------------------------------------------
// ROUND 8. R7 falsifier: fabric out_cnt atomics cost +30us in mega (102 vs
// 72) and +25us as scl loads in gather -> R7 reverted wholesale. Back to R6
// (best, 182.0): mega (build chunks + phase-S bkt2 || linear) + scale_tmp +
// sortgather. One targeted change: sortgather read the 12.3MB bucket grid
// TWICE (hist, reorder), ~48% invalid slots both times. Now the hist pass
// compacts valid entries into an LDS queue ent[] (1 LDS atomic per uint4),
// and reorder runs LDS->LDS -- second global scan deleted.
// mega and scale_tmp are BIT-IDENTICAL to R6.
// ---------------------------------------------------------------------------
struct BuildSmem { int dcur[MAXNB]; int scur[MAXNB]; };  // 4 KB
struct LinSmem { float w[IN_F * OUT_F]; };               // 16 KB
union MegaSmem { BuildSmem b; LinSmem l; };

__global__ __launch_bounds__(512) void mega_kernel(
    const int* __restrict__ src, const int* __restrict__ dst,
    const float* __restrict__ feat, const float* __restrict__ weight,
    int* __restrict__ out_cnt, int* __restrict__ in_cnt,
    unsigned* __restrict__ bkt, unsigned short* __restrict__ bkt2,
    unsigned short* __restrict__ cnts_d, unsigned short* __restrict__ cnts_s,
    int* __restrict__ ovf, int* __restrict__ ovf_cnt,
    __half* __restrict__ tmp, int n_edges, int n_nodes,
    int n_bbl, int n_lbl) {

    __shared__ MegaSmem sm;
    int tid = threadIdx.x;
    int bid = blockIdx.x;

    // interleave: every 3rd block is build (n_lbl ~= 2*n_bbl)
    int t = bid / 3, r = bid - 3 * t;
    bool is_build = (r == 0) && (t < n_bbl);
    int sub;
    if (is_build) sub = t;
    else {
        sub = bid - min(t + (r ? 1 : 0), n_bbl);
        if (sub >= n_lbl) return;
    }

    if (is_build) {
        int e0 = sub * EPB;
        int ecnt = min(EPB, n_edges - e0);
        int sD = n_bbl * C_D;            // u32 stride per dst bucket
        int sS = n_bbl * C_S;            // u16 stride per src bucket

        for (int i = tid; i < MAXNB; i += 512) {
            sm.b.dcur[i] = 0;
            sm.b.scur[i] = 0;
        }
        __syncthreads();

        int k4 = ecnt >> 2;
        const int4* src4 = (const int4*)(src + e0);
        const int4* dst4 = (const int4*)(dst + e0);

#define EDGE(ss, dd) {                                                        \
            int bin = (dd) >> RSHIFT;                                         \
            int idx = atomicAdd(&sm.b.dcur[bin], 1);                          \
            if (idx < C_D) {                                                  \
                bkt[(size_t)bin * sD + sub * C_D + idx] =                     \
                    ((unsigned)(ss) << RSHIFT) | (unsigned)((dd) & RMASK);    \
            } else {                                                          \
                atomicAdd(&in_cnt[dd], 1);                                    \
                int o = atomicAdd(ovf_cnt, 1);                                \
                if (o < OVF_CAP) { ovf[2 * o] = (ss); ovf[2 * o + 1] = (dd); }\
            }                                                                 \
            int b2 = (ss) >> RSHIFT;                                          \
            int i2 = atomicAdd(&sm.b.scur[b2], 1);                            \
            if (i2 < C_S) {                                                   \
                bkt2[(size_t)b2 * sS + sub * C_S + i2] =                      \
                    (unsigned short)((ss) & RMASK);                           \
            } else {                                                          \
                atomicAdd(&out_cnt[ss], 1);                                   \
            } }

        for (int k = tid; k < k4; k += 512) {
            int4 s4 = src4[k];
            int4 d4 = dst4[k];
            EDGE(s4.x, d4.x)
            EDGE(s4.y, d4.y)
            EDGE(s4.z, d4.z)
            EDGE(s4.w, d4.w)
        }
        for (int k = (k4 << 2) + tid; k < ecnt; k += 512) {
            int s = src[e0 + k], d = dst[e0 + k];
            EDGE(s, d)
        }
#undef EDGE
        __syncthreads();

        // publish exact per-(bin,block) counts
        for (int bin = tid; bin < MAXNB; bin += 512) {
            cnts_d[bin * MAXBBL + sub] = (unsigned short)min(sm.b.dcur[bin], C_D);
            cnts_s[bin * MAXBBL + sub] = (unsigned short)min(sm.b.scur[bin], C_S);
        }
    } else {
        // ===== linear: tmp(fp16) = feat @ W, UNSCALED (256 rows/block) =====
        for (int i = tid; i < IN_F * OUT_F / 4; i += 512)
            ((float4*)sm.l.w)[i] = ((const float4*)weight)[i];
        __syncthreads();

        int q  = tid >> 3;                  // 0..63 row-quads
        int cg = tid & 7;                   // col group of 4
        int row0 = sub * 256 + q * 4;
        if (row0 >= n_nodes) return;
        int rmax = n_nodes - row0;
        if (rmax > 4) rmax = 4;

        const float4* feat4 = (const float4*)feat;
        float4 acc[4];
#pragma unroll
        for (int rr = 0; rr < 4; ++rr) acc[rr] = make_float4(0.f, 0.f, 0.f, 0.f);

        for (int k4i = 0; k4i < IN_F / 4; ++k4i) {
            float4 wv0 = *(const float4*)&sm.l.w[(4 * k4i + 0) * OUT_F + 4 * cg];
            float4 wv1 = *(const float4*)&sm.l.w[(4 * k4i + 1) * OUT_F + 4 * cg];
            float4 wv2 = *(const float4*)&sm.l.w[(4 * k4i + 2) * OUT_F + 4 * cg];
            float4 wv3 = *(const float4*)&sm.l.w[(4 * k4i + 3) * OUT_F + 4 * cg];
#pragma unroll
            for (int rr = 0; rr < 4; ++rr) {
                int r2 = (rr < rmax) ? rr : 0;
                float4 f = feat4[(size_t)(row0 + r2) * (IN_F / 4) + k4i];
                acc[rr].x += f.x * wv0.x + f.y * wv1.x + f.z * wv2.x + f.w * wv3.x;
                acc[rr].y += f.x * wv0.y + f.y * wv1.y + f.z * wv2.y + f.w * wv3.y;
                acc[rr].z += f.x * wv0.z + f.y * wv1.z + f.z * wv2.z + f.w * wv3.z;
                acc[rr].w += f.x * wv0.w + f.y * wv1.w + f.z * wv2.w + f.w * wv3.w;
            }
        }

#pragma unroll
        for (int rr = 0; rr < 4; ++rr) {
            if (rr < rmax) {
                union { __half h[4]; uint2 u; } pk;
                pk.h[0] = __float2half(acc[rr].x);
                pk.h[1] = __float2half(acc[rr].y);
                pk.h[2] = __float2half(acc[rr].z);
                pk.h[3] = __float2half(acc[rr].w);
                *(uint2*)&tmp[(size_t)(row0 + rr) * OUT_F + 4 * cg] = pk.u;
            }
        }
    }
}

// ---------------------------------------------------------------------------
// scale_tmp: one 512-thr block per src-bucket. Scan [n_bbl][C_S] u16 grid
// with count validity, LDS-histogram low bytes -> out-degree -> fold rsqrt
// into tmp. (Bit-identical to R6.)
// ---------------------------------------------------------------------------
__global__ __launch_bounds__(512) void scale_tmp(
    const unsigned short* __restrict__ bkt2,
    const unsigned short* __restrict__ cnts_s,
    const int* __restrict__ out_cnt, __half* __restrict__ tmp,
    int n_nodes, int n_bbl) {
    __shared__ int hist[R_NODES];
    __shared__ float scf[R_NODES];
    __shared__ unsigned short cnt[MAXBBL];
    int b = blockIdx.x, tid = threadIdx.x;

    if (tid < R_NODES) hist[tid] = 0;
    for (int i = tid; i < n_bbl; i += 512) cnt[i] = cnts_s[b * MAXBBL + i];
    __syncthreads();

    int sS = n_bbl * C_S;
    const uint4* g4 = (const uint4*)(bkt2 + (size_t)b * sS);
    int n4 = sS >> 3;                       // 8 u16 entries per uint4
    for (int i = tid; i < n4; i += 512) {
        int e0 = i << 3;
        int c = e0 >> 5;                    // C_S = 32
        int w = e0 & 31;
        int cc = cnt[c];
        if (w >= cc) continue;              // fully invalid oct
        uint4 v = g4[i];
        unsigned e;
        e = v.x & 0xFFFF;             atomicAdd(&hist[e], 1);
        e = v.x >> 16;    if (w + 1 < cc) atomicAdd(&hist[e], 1);
        e = v.y & 0xFFFF; if (w + 2 < cc) atomicAdd(&hist[e], 1);
        e = v.y >> 16;    if (w + 3 < cc) atomicAdd(&hist[e], 1);
        e = v.z & 0xFFFF; if (w + 4 < cc) atomicAdd(&hist[e], 1);
        e = v.z >> 16;    if (w + 5 < cc) atomicAdd(&hist[e], 1);
        e = v.w & 0xFFFF; if (w + 6 < cc) atomicAdd(&hist[e], 1);
        e = v.w >> 16;    if (w + 7 < cc) atomicAdd(&hist[e], 1);
    }
    __syncthreads();

    if (tid < R_NODES) {
        int node = b * R_NODES + tid;
        if (node < n_nodes) {
            int deg = hist[tid] + out_cnt[node];   // + rare overflow adds
            scf[tid] = rsqrtf(fmaxf((float)deg, 1.0f));
        }
    }
    __syncthreads();

#pragma unroll
    for (int p = 0; p < 2; ++p) {
        int idx = p * 512 + tid;            // 0..1023 (node, quarter)
        int rr = idx >> 2;
        int nd = b * R_NODES + rr;
        if (nd >= n_nodes) continue;
        float sc = scf[rr];
        uint4* ptr = (uint4*)(tmp + (size_t)nd * OUT_F) + (idx & 3);
        uint4 v = *ptr;
        __half2* h = (__half2*)&v;
#pragma unroll
        for (int i = 0; i < 4; ++i) {
            float2 f = __half22float2(h[i]);
            f.x *= sc; f.y *= sc;
            h[i] = __float22half2_rn(f);
        }
        *ptr = v;
    }
}

// ---------------------------------------------------------------------------
// sortgather: one 1024-thr block per 256-node dst bucket. SINGLE grid pass:
// hist + compact valid entries into LDS ent[] queue; reorder LDS->LDS; then
// the proven 8-lane x uint2 gather.
// ---------------------------------------------------------------------------
__global__ __launch_bounds__(1024) void sortgather_kernel(
    const unsigned* __restrict__ bkt,
    const unsigned short* __restrict__ cnts_d,
    const int* __restrict__ in_cnt,
    const int* __restrict__ ovf, const int* __restrict__ ovf_cnt,
    const __half* __restrict__ tmp, float* __restrict__ out,
    int n_nodes, int n_bbl) {

    __shared__ unsigned ent[SRT_CAP];       // 24 KB compacted valid entries
    __shared__ unsigned srt[SRT_CAP];       // 24 KB (src ids, node-sorted)
    __shared__ unsigned short cnt[MAXBBL];
    __shared__ int hist[R_NODES];
    __shared__ int base[R_NODES];
    __shared__ int start[R_NODES];
    __shared__ int qcnt;

    int b = blockIdx.x, tid = threadIdx.x;

    if (tid < R_NODES) hist[tid] = 0;
    if (tid == 0) qcnt = 0;
    for (int i = tid; i < n_bbl; i += 1024) cnt[i] = cnts_d[b * MAXBBL + i];
    __syncthreads();

    int sD = n_bbl * C_D;
    const uint4* g4 = (const uint4*)(bkt + (size_t)b * sD);
    int n4 = sD >> 2;                       // 4 u32 entries per uint4 (4|C_D)

    // single grid pass: histogram + compact-stage into ent[]
    for (int i = tid; i < n4; i += 1024) {
        int e0 = i << 2;
        int c = e0 / C_D;                   // const-div -> magic mul
        int w = e0 - c * C_D;
        int cc = cnt[c];
        if (w >= cc) continue;
        uint4 v = g4[i];
        int vc = cc - w; if (vc > 4) vc = 4;
        int q = atomicAdd(&qcnt, vc);
        atomicAdd(&hist[v.x & RMASK], 1);
        if (q < SRT_CAP) ent[q] = v.x;
        if (vc > 1) { atomicAdd(&hist[v.y & RMASK], 1);
                      if (q + 1 < SRT_CAP) ent[q + 1] = v.y; }
        if (vc > 2) { atomicAdd(&hist[v.z & RMASK], 1);
                      if (q + 2 < SRT_CAP) ent[q + 2] = v.z; }
        if (vc > 3) { atomicAdd(&hist[v.w & RMASK], 1);
                      if (q + 3 < SRT_CAP) ent[q + 3] = v.w; }
    }
    __syncthreads();

    if (tid < 64) {                      // scan 256 bins, 4/lane
        int a0 = hist[4 * tid], a1 = hist[4 * tid + 1];
        int a2 = hist[4 * tid + 2], a3 = hist[4 * tid + 3];
        int s = a0 + a1 + a2 + a3;
        int sc = s;
        for (int off = 1; off < 64; off <<= 1) {
            int v = __shfl_up(sc, off, 64);
            if (tid >= off) sc += v;
        }
        int excl = sc - s;
        base[4 * tid]     = excl;
        base[4 * tid + 1] = excl + a0;
        base[4 * tid + 2] = excl + a0 + a1;
        base[4 * tid + 3] = excl + a0 + a1 + a2;
    }
    __syncthreads();
    if (tid < R_NODES) start[tid] = base[tid];
    __syncthreads();

    // reorder LDS -> LDS
    int ne = min(qcnt, SRT_CAP);
    for (int i = tid; i < ne; i += 1024) {
        unsigned v = ent[i];
        int p = atomicAdd(&base[v & RMASK], 1);
        if (p < SRT_CAP) srt[p] = v >> RSHIFT;
    }
    __syncthreads();

    int g = tid >> 3;                    // group 0..127
    int c = tid & 7;                     // uint2 (4-half) column group
    int n0 = b * R_NODES;
    int novf = min(*ovf_cnt, OVF_CAP);

    for (int ln = g; ln < R_NODES; ln += 128) {
        int node = n0 + ln;
        if (node >= n_nodes) continue;
        int cntn = hist[ln];
        int st   = start[ln];

        float a0 = 0.f, a1 = 0.f, a2 = 0.f, a3 = 0.f;
        float b0 = 0.f, b1 = 0.f, b2 = 0.f, b3 = 0.f;
        int j = 0;
        for (; j + 8 <= cntn; j += 8) {
            int s0 = (int)srt[st + j + 0], s1 = (int)srt[st + j + 1];
            int s2 = (int)srt[st + j + 2], s3 = (int)srt[st + j + 3];
            int s4 = (int)srt[st + j + 4], s5 = (int)srt[st + j + 5];
            int s6 = (int)srt[st + j + 6], s7 = (int)srt[st + j + 7];
            uint2 v0 = *(const uint2*)(tmp + (size_t)s0 * OUT_F + 4 * c);
            uint2 v1 = *(const uint2*)(tmp + (size_t)s1 * OUT_F + 4 * c);
            uint2 v2 = *(const uint2*)(tmp + (size_t)s2 * OUT_F + 4 * c);
            uint2 v3 = *(const uint2*)(tmp + (size_t)s3 * OUT_F + 4 * c);
            uint2 v4 = *(const uint2*)(tmp + (size_t)s4 * OUT_F + 4 * c);
            uint2 v5 = *(const uint2*)(tmp + (size_t)s5 * OUT_F + 4 * c);
            uint2 v6 = *(const uint2*)(tmp + (size_t)s6 * OUT_F + 4 * c);
            uint2 v7 = *(const uint2*)(tmp + (size_t)s7 * OUT_F + 4 * c);
            const __half2* h;
            float2 f;
            h = (const __half2*)&v0;
            f = __half22float2(h[0]); a0 += f.x; a1 += f.y;
            f = __half22float2(h[1]); a2 += f.x; a3 += f.y;
            h = (const __half2*)&v1;
            f = __half22float2(h[0]); b0 += f.x; b1 += f.y;
            f = __half22float2(h[1]); b2 += f.x; b3 += f.y;
            h = (const __half2*)&v2;
            f = __half22float2(h[0]); a0 += f.x; a1 += f.y;
            f = __half22float2(h[1]); a2 += f.x; a3 += f.y;
            h = (const __half2*)&v3;
            f = __half22float2(h[0]); b0 += f.x; b1 += f.y;
            f = __half22float2(h[1]); b2 += f.x; b3 += f.y;
            h = (const __half2*)&v4;
            f = __half22float2(h[0]); a0 += f.x; a1 += f.y;
            f = __half22float2(h[1]); a2 += f.x; a3 += f.y;
            h = (const __half2*)&v5;
            f = __half22float2(h[0]); b0 += f.x; b1 += f.y;
            f = __half22float2(h[1]); b2 += f.x; b3 += f.y;
            h = (const __half2*)&v6;
            f = __half22float2(h[0]); a0 += f.x; a1 += f.y;
            f = __half22float2(h[1]); a2 += f.x; a3 += f.y;
            h = (const __half2*)&v7;
            f = __half22float2(h[0]); b0 += f.x; b1 += f.y;
            f = __half22float2(h[1]); b2 += f.x; b3 += f.y;
        }
        for (; j < cntn; ++j) {
            int s = (int)srt[st + j];
            uint2 v = *(const uint2*)(tmp + (size_t)s * OUT_F + 4 * c);
            const __half2* h = (const __half2*)&v;
            float2 f;
            if (j & 1) {
                f = __half22float2(h[0]); b0 += f.x; b1 += f.y;
                f = __half22float2(h[1]); b2 += f.x; b3 += f.y;
            } else {
                f = __half22float2(h[0]); a0 += f.x; a1 += f.y;
                f = __half22float2(h[1]); a2 += f.x; a3 += f.y;
            }
        }
        for (int e2 = 0; e2 < novf; ++e2) {        // ~always empty
            if (ovf[2 * e2 + 1] == node) {
                uint2 v = *(const uint2*)(tmp + (size_t)ovf[2 * e2] * OUT_F + 4 * c);
                const __half2* h = (const __half2*)&v;
                float2 f;
                f = __half22float2(h[0]); a0 += f.x; a1 += f.y;
                f = __half22float2(h[1]); a2 += f.x; a3 += f.y;
            }
        }

        float dg = (float)(cntn + in_cnt[node]);
        float sc = rsqrtf(fmaxf(dg, 1.0f));
        float4 o = make_float4((a0 + b0) * sc, (a1 + b1) * sc,
                               (a2 + b2) * sc, (a3 + b3) * sc);
        *(float4*)(out + (size_t)node * OUT_F + 4 * c) = o;
    }
}

// ---------------------------------------------------------------------------
// Fallback path (ws too small): degree + scaled-linear + atomic scatter.
// ---------------------------------------------------------------------------
__global__ void degree_kernel(const int* __restrict__ src, const int* __restrict__ dst,
                              int* __restrict__ out_cnt, int* __restrict__ in_cnt,
                              int n_edges) {
    int i = blockIdx.x * blockDim.x + threadIdx.x;
    if (i < n_edges) {
        atomicAdd(&out_cnt[src[i]], 1);
        atomicAdd(&in_cnt[dst[i]], 1);
    }
}

__global__ __launch_bounds__(256) void linear_fb(const float* __restrict__ feat,
                                                 const float* __restrict__ weight,
                                                 const int* __restrict__ out_cnt,
                                                 __half* __restrict__ tmp, int n_nodes) {
    __shared__ float w[IN_F * OUT_F];
    {
        const float4* wg = (const float4*)weight;
        float4* wsh = (float4*)w;
        for (int i = threadIdx.x; i < IN_F * OUT_F / 4; i += 256) wsh[i] = wg[i];
    }
    __syncthreads();
    int q  = threadIdx.x >> 3;
    int cg = threadIdx.x & 7;
    int row0 = blockIdx.x * 128 + q * 4;
    if (row0 >= n_nodes) return;
    int rmax = n_nodes - row0;
    if (rmax > 4) rmax = 4;
    const float4* feat4 = (const float4*)feat;
    float4 acc[4];
#pragma unroll
    for (int r = 0; r < 4; ++r) acc[r] = make_float4(0.f, 0.f, 0.f, 0.f);
    for (int k4 = 0; k4 < IN_F / 4; ++k4) {
        float4 wv0 = *(const float4*)&w[(4 * k4 + 0) * OUT_F + 4 * cg];
        float4 wv1 = *(const float4*)&w[(4 * k4 + 1) * OUT_F + 4 * cg];
        float4 wv2 = *(const float4*)&w[(4 * k4 + 2) * OUT_F + 4 * cg];
        float4 wv3 = *(const float4*)&w[(4 * k4 + 3) * OUT_F + 4 * cg];
#pragma unroll
        for (int r = 0; r < 4; ++r) {
            int rr = (r < rmax) ? r : 0;
            float4 f = feat4[(size_t)(row0 + rr) * (IN_F / 4) + k4];
            acc[r].x += f.x * wv0.x + f.y * wv1.x + f.z * wv2.x + f.w * wv3.x;
            acc[r].y += f.x * wv0.y + f.y * wv1.y + f.z * wv2.y + f.w * wv3.y;
            acc[r].z += f.x * wv0.z + f.y * wv1.z + f.z * wv2.z + f.w * wv3.z;
            acc[r].w += f.x * wv0.w + f.y * wv1.w + f.z * wv2.w + f.w * wv3.w;
        }
    }
#pragma unroll
    for (int r = 0; r < 4; ++r) {
        if (r < rmax) {
            float sc = rsqrtf(fmaxf((float)out_cnt[row0 + r], 1.0f));
            union { __half h[4]; uint2 u; } pk;
            pk.h[0] = __float2half(acc[r].x * sc);
            pk.h[1] = __float2half(acc[r].y * sc);
            pk.h[2] = __float2half(acc[r].z * sc);
            pk.h[3] = __float2half(acc[r].w * sc);
            *(uint2*)&tmp[(size_t)(row0 + r) * OUT_F + 4 * cg] = pk.u;
        }
    }
}

__global__ void scatter_kernel(const int* __restrict__ src, const int* __restrict__ dst,
                               const __half* __restrict__ tmp, float* __restrict__ out,
                               int n_edges) {
    long long t = (long long)blockIdx.x * blockDim.x + threadIdx.x;
    int e = (int)(t >> 5);
    int c = (int)(t & (OUT_F - 1));
    if (e < n_edges) {
        atomicAdd(&out[(size_t)dst[e] * OUT_F + c],
                  __half2float(tmp[(size_t)src[e] * OUT_F + c]));
    }
}

__global__ void finalize_kernel(float* __restrict__ out, const int* __restrict__ in_cnt,
                                int n_total) {
    int t = blockIdx.x * blockDim.x + threadIdx.x;
    if (t < n_total) {
        out[t] *= rsqrtf(fmaxf((float)in_cnt[t >> 5], 1.0f));
    }
}

extern "C" void kernel_launch(void* const* d_in, const int* in_sizes, int n_in,
                              void* d_out, int out_size, void* d_ws, size_t ws_size,
                              hipStream_t stream) {
    const float* feat   = (const float*)d_in[0];
    const int*   src    = (const int*)d_in[1];
    const int*   dst    = (const int*)d_in[2];
    const float* weight = (const float*)d_in[3];
    float*       out    = (float*)d_out;

    int n_nodes = in_sizes[0] / IN_F;   // 100000
    int n_edges = in_sizes[1];          // 1600000
    int n_buckets = (n_nodes + R_NODES - 1) / R_NODES;  // 391
    int n_bbl = (n_edges + EPB - 1) / EPB;              // 196
    int n_lbl = (n_nodes + 255) / 256;                  // 391

    // ws layout: [out_cnt n][in_cnt n][ovf_cnt 8][ovf 2*CAP]
    //            [cnts_d MAXNB*MAXBBL u16][cnts_s same]
    //            [bkt nb x n_bbl*C_D u32][bkt2 nb x n_bbl*C_S u16][tmp]
    int*      out_cnt = (int*)d_ws;
    int*      in_cnt  = out_cnt + n_nodes;
    int*      ovf_cnt = in_cnt + n_nodes;
    int*      ovf     = ovf_cnt + 8;
    unsigned short* cnts_d = (unsigned short*)(ovf + 2 * OVF_CAP);
    unsigned short* cnts_s = cnts_d + (size_t)MAXNB * MAXBBL;
    char*     bkt_raw = (char*)(cnts_s + (size_t)MAXNB * MAXBBL);
    unsigned* bkt     = (unsigned*)(((uintptr_t)bkt_raw + 15) & ~(uintptr_t)15);
    int sD = n_bbl * C_D;
    int sS = n_bbl * C_S;
    unsigned short* bkt2 = (unsigned short*)(bkt + (size_t)n_buckets * sD);
    char*     tmp_raw = (char*)(bkt2 + (size_t)n_buckets * sS);
    __half*   tmp     = (__half*)(((uintptr_t)tmp_raw + 15) & ~(uintptr_t)15);
    size_t    needed  = (char*)(tmp + (size_t)n_nodes * OUT_F) - (char*)d_ws;

    if (ws_size >= needed && n_buckets <= MAXNB && n_bbl <= MAXBBL) {
        hipMemsetAsync(out_cnt, 0, ((size_t)2 * n_nodes + 8) * sizeof(int), stream);
        mega_kernel<<<n_bbl + n_lbl, 512, 0, stream>>>(
            src, dst, feat, weight, out_cnt, in_cnt, bkt, bkt2,
            cnts_d, cnts_s, ovf, ovf_cnt, tmp, n_edges, n_nodes, n_bbl, n_lbl);
        scale_tmp<<<n_buckets, 512, 0, stream>>>(
            bkt2, cnts_s, out_cnt, tmp, n_nodes, n_bbl);
        sortgather_kernel<<<n_buckets, 1024, 0, stream>>>(
            bkt, cnts_d, in_cnt, ovf, ovf_cnt, tmp, out, n_nodes, n_bbl);
    } else {
        // fallback: atomic scatter
        __half* tmp_fb = (__half*)(ovf + 2 * OVF_CAP);
        hipMemsetAsync(out_cnt, 0, ((size_t)2 * n_nodes + 8) * sizeof(int), stream);
        hipMemsetAsync(d_out, 0, (size_t)out_size * sizeof(float), stream);
        degree_kernel<<<(n_edges + 255) / 256, 256, 0, stream>>>(src, dst, out_cnt, in_cnt, n_edges);
        linear_fb<<<(n_nodes + 127) / 128, 256, 0, stream>>>(feat, weight, out_cnt, tmp_fb, n_nodes);
        long long st = (long long)n_edges * OUT_F;
        scatter_kernel<<<(int)((st + 255) / 256), 256, 0, stream>>>(src, dst, tmp_fb, out, n_edges);
        finalize_kernel<<<(n_nodes * OUT_F + 255) / 256, 256, 0, stream>>>(out, in_cnt, n_nodes * OUT_F);
    }
}

// Round 10
// 170.047 us; speedup vs baseline: 1.3005x; 1.1077x over previous
//
#include <hip/hip_runtime.h>
#include <hip/hip_fp16.h>

#define IN_F 128
#define OUT_F 32
#define R_NODES 256          // dst nodes per bucket (8 bits)
#define RSHIFT 8
#define RMASK 255
#define OVF_CAP 4096
#define EPB 8192             // edges per build sub-block
#define MAXNB 512            // max bins => n_nodes <= 131072
#define MAXBBL 256           // max build blocks => n_edges <= 2.09M
#define C_D 40               // dst chunk cap: P(Poisson(21)>40) ~ 5e-5 per chunk
#define C_S 32               // src chunk cap (u8): overflow -> fabric atomic (rare)
#define SRT_CAP 6144         // per-bucket edge cap (mean 4092)

// ---------------------------------------------------------------------------
// ROUND 10 = ROUND 9 + one-line OOB fix. R9's NaN: the dense S-chunk flush
// iterated bin < MAXNB (512) but bkt2 is allocated for n_buckets (391)
// buckets -> bins 391..511 wrote ~759KB past bkt2 into tmp (garbage fp16 ->
// NaN). Fix: flush/publish loop capped at nb = ceil(n_nodes/256). The R9
// hypothesis (S-side scatter-stores -> whole-32B-chunk stores, 16x fewer
// random-granule transactions) is hereby actually tested.
// ---------------------------------------------------------------------------
struct BuildSmem {
    int dcur[MAXNB];                     // 2 KB
    int scur[MAXNB];                     // 2 KB
    unsigned char su8[MAXNB * C_S];      // 16 KB staged S-chunks
};
struct LinSmem { float w[IN_F * OUT_F]; };               // 16 KB
union MegaSmem { BuildSmem b; LinSmem l; };

__global__ __launch_bounds__(512) void mega_kernel(
    const int* __restrict__ src, const int* __restrict__ dst,
    const float* __restrict__ feat, const float* __restrict__ weight,
    int* __restrict__ out_cnt, int* __restrict__ in_cnt,
    unsigned* __restrict__ bkt, unsigned char* __restrict__ bkt2,
    unsigned short* __restrict__ cnts_d, unsigned short* __restrict__ cnts_s,
    int* __restrict__ ovf, int* __restrict__ ovf_cnt,
    __half* __restrict__ tmp, int n_edges, int n_nodes,
    int n_bbl, int n_lbl) {

    __shared__ MegaSmem sm;
    int tid = threadIdx.x;
    int bid = blockIdx.x;

    // interleave: every 3rd block is build (n_lbl ~= 2*n_bbl)
    int t = bid / 3, r = bid - 3 * t;
    bool is_build = (r == 0) && (t < n_bbl);
    int sub;
    if (is_build) sub = t;
    else {
        sub = bid - min(t + (r ? 1 : 0), n_bbl);
        if (sub >= n_lbl) return;
    }

    if (is_build) {
        int e0 = sub * EPB;
        int ecnt = min(EPB, n_edges - e0);
        int sD = n_bbl * C_D;            // u32 stride per dst bucket
        int sS = n_bbl * C_S;            // u8  stride per src bucket

        for (int i = tid; i < MAXNB; i += 512) {
            sm.b.dcur[i] = 0;
            sm.b.scur[i] = 0;
        }
        __syncthreads();

        int k4 = ecnt >> 2;
        const int4* src4 = (const int4*)(src + e0);
        const int4* dst4 = (const int4*)(dst + e0);

#define EDGE(ss, dd) {                                                        \
            int bin = (dd) >> RSHIFT;                                         \
            int idx = atomicAdd(&sm.b.dcur[bin], 1);                          \
            if (idx < C_D) {                                                  \
                bkt[(size_t)bin * sD + sub * C_D + idx] =                     \
                    ((unsigned)(ss) << RSHIFT) | (unsigned)((dd) & RMASK);    \
            } else {                                                          \
                atomicAdd(&in_cnt[dd], 1);                                    \
                int o = atomicAdd(ovf_cnt, 1);                                \
                if (o < OVF_CAP) { ovf[2 * o] = (ss); ovf[2 * o + 1] = (dd); }\
            }                                                                 \
            int b2 = (ss) >> RSHIFT;                                          \
            int i2 = atomicAdd(&sm.b.scur[b2], 1);                            \
            if (i2 < C_S) {                                                   \
                sm.b.su8[b2 * C_S + i2] = (unsigned char)((ss) & RMASK);      \
            } else {                                                          \
                atomicAdd(&out_cnt[ss], 1);                                   \
            } }

        for (int k = tid; k < k4; k += 512) {
            int4 s4 = src4[k];
            int4 d4 = dst4[k];
            EDGE(s4.x, d4.x)
            EDGE(s4.y, d4.y)
            EDGE(s4.z, d4.z)
            EDGE(s4.w, d4.w)
        }
        for (int k = (k4 << 2) + tid; k < ecnt; k += 512) {
            int s = src[e0 + k], d = dst[e0 + k];
            EDGE(s, d)
        }
#undef EDGE
        __syncthreads();

        // flush whole 32B S-chunks + publish counts -- ONLY for real buckets
        int nb = (n_nodes + R_NODES - 1) >> RSHIFT;     // == n_buckets
        for (int bin = tid; bin < nb; bin += 512) {
            uint4* dp = (uint4*)(bkt2 + (size_t)bin * sS + sub * C_S);
            const uint4* sp = (const uint4*)&sm.b.su8[bin * C_S];
            dp[0] = sp[0];
            dp[1] = sp[1];
            cnts_d[bin * MAXBBL + sub] = (unsigned short)min(sm.b.dcur[bin], C_D);
            cnts_s[bin * MAXBBL + sub] = (unsigned short)min(sm.b.scur[bin], C_S);
        }
    } else {
        // ===== linear: tmp(fp16) = feat @ W, UNSCALED (256 rows/block) =====
        for (int i = tid; i < IN_F * OUT_F / 4; i += 512)
            ((float4*)sm.l.w)[i] = ((const float4*)weight)[i];
        __syncthreads();

        int q  = tid >> 3;                  // 0..63 row-quads
        int cg = tid & 7;                   // col group of 4
        int row0 = sub * 256 + q * 4;
        if (row0 >= n_nodes) return;
        int rmax = n_nodes - row0;
        if (rmax > 4) rmax = 4;

        const float4* feat4 = (const float4*)feat;
        float4 acc[4];
#pragma unroll
        for (int rr = 0; rr < 4; ++rr) acc[rr] = make_float4(0.f, 0.f, 0.f, 0.f);

        for (int k4i = 0; k4i < IN_F / 4; ++k4i) {
            float4 wv0 = *(const float4*)&sm.l.w[(4 * k4i + 0) * OUT_F + 4 * cg];
            float4 wv1 = *(const float4*)&sm.l.w[(4 * k4i + 1) * OUT_F + 4 * cg];
            float4 wv2 = *(const float4*)&sm.l.w[(4 * k4i + 2) * OUT_F + 4 * cg];
            float4 wv3 = *(const float4*)&sm.l.w[(4 * k4i + 3) * OUT_F + 4 * cg];
#pragma unroll
            for (int rr = 0; rr < 4; ++rr) {
                int r2 = (rr < rmax) ? rr : 0;
                float4 f = feat4[(size_t)(row0 + r2) * (IN_F / 4) + k4i];
                acc[rr].x += f.x * wv0.x + f.y * wv1.x + f.z * wv2.x + f.w * wv3.x;
                acc[rr].y += f.x * wv0.y + f.y * wv1.y + f.z * wv2.y + f.w * wv3.y;
                acc[rr].z += f.x * wv0.z + f.y * wv1.z + f.z * wv2.z + f.w * wv3.z;
                acc[rr].w += f.x * wv0.w + f.y * wv1.w + f.z * wv2.w + f.w * wv3.w;
            }
        }

#pragma unroll
        for (int rr = 0; rr < 4; ++rr) {
            if (rr < rmax) {
                union { __half h[4]; uint2 u; } pk;
                pk.h[0] = __float2half(acc[rr].x);
                pk.h[1] = __float2half(acc[rr].y);
                pk.h[2] = __float2half(acc[rr].z);
                pk.h[3] = __float2half(acc[rr].w);
                *(uint2*)&tmp[(size_t)(row0 + rr) * OUT_F + 4 * cg] = pk.u;
            }
        }
    }
}

// ---------------------------------------------------------------------------
// scale_tmp: one 512-thr block per src-bucket. Scan [n_bbl][C_S] u8 grid
// (uint4 = 16 entries) with count validity, LDS-histogram -> out-degree ->
// fold rsqrt into tmp.
// ---------------------------------------------------------------------------
__global__ __launch_bounds__(512) void scale_tmp(
    const unsigned char* __restrict__ bkt2,
    const unsigned short* __restrict__ cnts_s,
    const int* __restrict__ out_cnt, __half* __restrict__ tmp,
    int n_nodes, int n_bbl) {
    __shared__ int hist[R_NODES];
    __shared__ float scf[R_NODES];
    __shared__ unsigned short cnt[MAXBBL];
    int b = blockIdx.x, tid = threadIdx.x;

    if (tid < R_NODES) hist[tid] = 0;
    for (int i = tid; i < n_bbl; i += 512) cnt[i] = cnts_s[b * MAXBBL + i];
    __syncthreads();

    int sS = n_bbl * C_S;                   // bytes
    const uint4* g4 = (const uint4*)(bkt2 + (size_t)b * sS);
    int n4 = sS >> 4;                       // 16 u8 entries per uint4
    for (int i = tid; i < n4; i += 512) {
        int e0 = i << 4;
        int c = e0 >> 5;                    // C_S = 32
        int w = e0 & 31;
        int cc = cnt[c];
        if (w >= cc) continue;              // fully invalid 16-group
        uint4 v = g4[i];
#define HW_(word, base) {                                                     \
            unsigned ww = (word);                                             \
            if (w + (base) + 0 < cc) atomicAdd(&hist[ww & 255], 1);           \
            if (w + (base) + 1 < cc) atomicAdd(&hist[(ww >> 8) & 255], 1);    \
            if (w + (base) + 2 < cc) atomicAdd(&hist[(ww >> 16) & 255], 1);   \
            if (w + (base) + 3 < cc) atomicAdd(&hist[ww >> 24], 1); }
        HW_(v.x, 0)
        HW_(v.y, 4)
        HW_(v.z, 8)
        HW_(v.w, 12)
#undef HW_
    }
    __syncthreads();

    if (tid < R_NODES) {
        int node = b * R_NODES + tid;
        if (node < n_nodes) {
            int deg = hist[tid] + out_cnt[node];   // + rare overflow adds
            scf[tid] = rsqrtf(fmaxf((float)deg, 1.0f));
        }
    }
    __syncthreads();

#pragma unroll
    for (int p = 0; p < 2; ++p) {
        int idx = p * 512 + tid;            // 0..1023 (node, quarter)
        int rr = idx >> 2;
        int nd = b * R_NODES + rr;
        if (nd >= n_nodes) continue;
        float sc = scf[rr];
        uint4* ptr = (uint4*)(tmp + (size_t)nd * OUT_F) + (idx & 3);
        uint4 v = *ptr;
        __half2* h = (__half2*)&v;
#pragma unroll
        for (int i = 0; i < 4; ++i) {
            float2 f = __half22float2(h[i]);
            f.x *= sc; f.y *= sc;
            h[i] = __float22half2_rn(f);
        }
        *ptr = v;
    }
}

// ---------------------------------------------------------------------------
// sortgather: one 1024-thr block per 256-node dst bucket (R6 bit-pattern).
// Two grid scans (hist, reorder) with count validity, then 8-lane x uint2
// gather with 128 parallel node-groups and 8-deep load batching.
// ---------------------------------------------------------------------------
__global__ __launch_bounds__(1024) void sortgather_kernel(
    const unsigned* __restrict__ bkt,
    const unsigned short* __restrict__ cnts_d,
    const int* __restrict__ in_cnt,
    const int* __restrict__ ovf, const int* __restrict__ ovf_cnt,
    const __half* __restrict__ tmp, float* __restrict__ out,
    int n_nodes, int n_bbl) {

    __shared__ unsigned srt[SRT_CAP];       // 24 KB (src ids, node-sorted)
    __shared__ unsigned short cnt[MAXBBL];
    __shared__ int hist[R_NODES];
    __shared__ int base[R_NODES];
    __shared__ int start[R_NODES];

    int b = blockIdx.x, tid = threadIdx.x;

    if (tid < R_NODES) hist[tid] = 0;
    for (int i = tid; i < n_bbl; i += 1024) cnt[i] = cnts_d[b * MAXBBL + i];
    __syncthreads();

    int sD = n_bbl * C_D;
    const uint4* g4 = (const uint4*)(bkt + (size_t)b * sD);
    int n4 = sD >> 2;                       // 4 u32 entries per uint4 (4|C_D)

    for (int i = tid; i < n4; i += 1024) {
        int e0 = i << 2;
        int c = e0 / C_D;                   // const-div -> magic mul
        int w = e0 - c * C_D;
        int cc = cnt[c];
        if (w >= cc) continue;
        uint4 v = g4[i];
        atomicAdd(&hist[v.x & RMASK], 1);
        if (w + 1 < cc) atomicAdd(&hist[v.y & RMASK], 1);
        if (w + 2 < cc) atomicAdd(&hist[v.z & RMASK], 1);
        if (w + 3 < cc) atomicAdd(&hist[v.w & RMASK], 1);
    }
    __syncthreads();

    if (tid < 64) {                      // scan 256 bins, 4/lane
        int a0 = hist[4 * tid], a1 = hist[4 * tid + 1];
        int a2 = hist[4 * tid + 2], a3 = hist[4 * tid + 3];
        int s = a0 + a1 + a2 + a3;
        int sc = s;
        for (int off = 1; off < 64; off <<= 1) {
            int v = __shfl_up(sc, off, 64);
            if (tid >= off) sc += v;
        }
        int excl = sc - s;
        base[4 * tid]     = excl;
        base[4 * tid + 1] = excl + a0;
        base[4 * tid + 2] = excl + a0 + a1;
        base[4 * tid + 3] = excl + a0 + a1 + a2;
    }
    __syncthreads();
    if (tid < R_NODES) start[tid] = base[tid];
    __syncthreads();

    for (int i = tid; i < n4; i += 1024) {
        int e0 = i << 2;
        int c = e0 / C_D;
        int w = e0 - c * C_D;
        int cc = cnt[c];
        if (w >= cc) continue;
        uint4 v = g4[i];
        int p;
        p = atomicAdd(&base[v.x & RMASK], 1);
        if (p < SRT_CAP) srt[p] = v.x >> RSHIFT;
        if (w + 1 < cc) { p = atomicAdd(&base[v.y & RMASK], 1);
                          if (p < SRT_CAP) srt[p] = v.y >> RSHIFT; }
        if (w + 2 < cc) { p = atomicAdd(&base[v.z & RMASK], 1);
                          if (p < SRT_CAP) srt[p] = v.z >> RSHIFT; }
        if (w + 3 < cc) { p = atomicAdd(&base[v.w & RMASK], 1);
                          if (p < SRT_CAP) srt[p] = v.w >> RSHIFT; }
    }
    __syncthreads();

    int g = tid >> 3;                    // group 0..127
    int c = tid & 7;                     // uint2 (4-half) column group
    int n0 = b * R_NODES;
    int novf = min(*ovf_cnt, OVF_CAP);

    for (int ln = g; ln < R_NODES; ln += 128) {
        int node = n0 + ln;
        if (node >= n_nodes) continue;
        int cntn = hist[ln];
        int st   = start[ln];

        float a0 = 0.f, a1 = 0.f, a2 = 0.f, a3 = 0.f;
        float b0 = 0.f, b1 = 0.f, b2 = 0.f, b3 = 0.f;
        int j = 0;
        for (; j + 8 <= cntn; j += 8) {
            int s0 = (int)srt[st + j + 0], s1 = (int)srt[st + j + 1];
            int s2 = (int)srt[st + j + 2], s3 = (int)srt[st + j + 3];
            int s4 = (int)srt[st + j + 4], s5 = (int)srt[st + j + 5];
            int s6 = (int)srt[st + j + 6], s7 = (int)srt[st + j + 7];
            uint2 v0 = *(const uint2*)(tmp + (size_t)s0 * OUT_F + 4 * c);
            uint2 v1 = *(const uint2*)(tmp + (size_t)s1 * OUT_F + 4 * c);
            uint2 v2 = *(const uint2*)(tmp + (size_t)s2 * OUT_F + 4 * c);
            uint2 v3 = *(const uint2*)(tmp + (size_t)s3 * OUT_F + 4 * c);
            uint2 v4 = *(const uint2*)(tmp + (size_t)s4 * OUT_F + 4 * c);
            uint2 v5 = *(const uint2*)(tmp + (size_t)s5 * OUT_F + 4 * c);
            uint2 v6 = *(const uint2*)(tmp + (size_t)s6 * OUT_F + 4 * c);
            uint2 v7 = *(const uint2*)(tmp + (size_t)s7 * OUT_F + 4 * c);
            const __half2* h;
            float2 f;
            h = (const __half2*)&v0;
            f = __half22float2(h[0]); a0 += f.x; a1 += f.y;
            f = __half22float2(h[1]); a2 += f.x; a3 += f.y;
            h = (const __half2*)&v1;
            f = __half22float2(h[0]); b0 += f.x; b1 += f.y;
            f = __half22float2(h[1]); b2 += f.x; b3 += f.y;
            h = (const __half2*)&v2;
            f = __half22float2(h[0]); a0 += f.x; a1 += f.y;
            f = __half22float2(h[1]); a2 += f.x; a3 += f.y;
            h = (const __half2*)&v3;
            f = __half22float2(h[0]); b0 += f.x; b1 += f.y;
            f = __half22float2(h[1]); b2 += f.x; b3 += f.y;
            h = (const __half2*)&v4;
            f = __half22float2(h[0]); a0 += f.x; a1 += f.y;
            f = __half22float2(h[1]); a2 += f.x; a3 += f.y;
            h = (const __half2*)&v5;
            f = __half22float2(h[0]); b0 += f.x; b1 += f.y;
            f = __half22float2(h[1]); b2 += f.x; b3 += f.y;
            h = (const __half2*)&v6;
            f = __half22float2(h[0]); a0 += f.x; a1 += f.y;
            f = __half22float2(h[1]); a2 += f.x; a3 += f.y;
            h = (const __half2*)&v7;
            f = __half22float2(h[0]); b0 += f.x; b1 += f.y;
            f = __half22float2(h[1]); b2 += f.x; b3 += f.y;
        }
        for (; j < cntn; ++j) {
            int s = (int)srt[st + j];
            uint2 v = *(const uint2*)(tmp + (size_t)s * OUT_F + 4 * c);
            const __half2* h = (const __half2*)&v;
            float2 f;
            if (j & 1) {
                f = __half22float2(h[0]); b0 += f.x; b1 += f.y;
                f = __half22float2(h[1]); b2 += f.x; b3 += f.y;
            } else {
                f = __half22float2(h[0]); a0 += f.x; a1 += f.y;
                f = __half22float2(h[1]); a2 += f.x; a3 += f.y;
            }
        }
        for (int e2 = 0; e2 < novf; ++e2) {        // ~always empty
            if (ovf[2 * e2 + 1] == node) {
                uint2 v = *(const uint2*)(tmp + (size_t)ovf[2 * e2] * OUT_F + 4 * c);
                const __half2* h = (const __half2*)&v;
                float2 f;
                f = __half22float2(h[0]); a0 += f.x; a1 += f.y;
                f = __half22float2(h[1]); a2 += f.x; a3 += f.y;
            }
        }

        float dg = (float)(cntn + in_cnt[node]);
        float sc = rsqrtf(fmaxf(dg, 1.0f));
        float4 o = make_float4((a0 + b0) * sc, (a1 + b1) * sc,
                               (a2 + b2) * sc, (a3 + b3) * sc);
        *(float4*)(out + (size_t)node * OUT_F + 4 * c) = o;
    }
}

// ---------------------------------------------------------------------------
// Fallback path (ws too small): degree + scaled-linear + atomic scatter.
// ---------------------------------------------------------------------------
__global__ void degree_kernel(const int* __restrict__ src, const int* __restrict__ dst,
                              int* __restrict__ out_cnt, int* __restrict__ in_cnt,
                              int n_edges) {
    int i = blockIdx.x * blockDim.x + threadIdx.x;
    if (i < n_edges) {
        atomicAdd(&out_cnt[src[i]], 1);
        atomicAdd(&in_cnt[dst[i]], 1);
    }
}

__global__ __launch_bounds__(256) void linear_fb(const float* __restrict__ feat,
                                                 const float* __restrict__ weight,
                                                 const int* __restrict__ out_cnt,
                                                 __half* __restrict__ tmp, int n_nodes) {
    __shared__ float w[IN_F * OUT_F];
    {
        const float4* wg = (const float4*)weight;
        float4* wsh = (float4*)w;
        for (int i = threadIdx.x; i < IN_F * OUT_F / 4; i += 256) wsh[i] = wg[i];
    }
    __syncthreads();
    int q  = threadIdx.x >> 3;
    int cg = threadIdx.x & 7;
    int row0 = blockIdx.x * 128 + q * 4;
    if (row0 >= n_nodes) return;
    int rmax = n_nodes - row0;
    if (rmax > 4) rmax = 4;
    const float4* feat4 = (const float4*)feat;
    float4 acc[4];
#pragma unroll
    for (int r = 0; r < 4; ++r) acc[r] = make_float4(0.f, 0.f, 0.f, 0.f);
    for (int k4 = 0; k4 < IN_F / 4; ++k4) {
        float4 wv0 = *(const float4*)&w[(4 * k4 + 0) * OUT_F + 4 * cg];
        float4 wv1 = *(const float4*)&w[(4 * k4 + 1) * OUT_F + 4 * cg];
        float4 wv2 = *(const float4*)&w[(4 * k4 + 2) * OUT_F + 4 * cg];
        float4 wv3 = *(const float4*)&w[(4 * k4 + 3) * OUT_F + 4 * cg];
#pragma unroll
        for (int r = 0; r < 4; ++r) {
            int rr = (r < rmax) ? r : 0;
            float4 f = feat4[(size_t)(row0 + rr) * (IN_F / 4) + k4];
            acc[r].x += f.x * wv0.x + f.y * wv1.x + f.z * wv2.x + f.w * wv3.x;
            acc[r].y += f.x * wv0.y + f.y * wv1.y + f.z * wv2.y + f.w * wv3.y;
            acc[r].z += f.x * wv0.z + f.y * wv1.z + f.z * wv2.z + f.w * wv3.z;
            acc[r].w += f.x * wv0.w + f.y * wv1.w + f.z * wv2.w + f.w * wv3.w;
        }
    }
#pragma unroll
    for (int r = 0; r < 4; ++r) {
        if (r < rmax) {
            float sc = rsqrtf(fmaxf((float)out_cnt[row0 + r], 1.0f));
            union { __half h[4]; uint2 u; } pk;
            pk.h[0] = __float2half(acc[r].x * sc);
            pk.h[1] = __float2half(acc[r].y * sc);
            pk.h[2] = __float2half(acc[r].z * sc);
            pk.h[3] = __float2half(acc[r].w * sc);
            *(uint2*)&tmp[(size_t)(row0 + r) * OUT_F + 4 * cg] = pk.u;
        }
    }
}

__global__ void scatter_kernel(const int* __restrict__ src, const int* __restrict__ dst,
                               const __half* __restrict__ tmp, float* __restrict__ out,
                               int n_edges) {
    long long t = (long long)blockIdx.x * blockDim.x + threadIdx.x;
    int e = (int)(t >> 5);
    int c = (int)(t & (OUT_F - 1));
    if (e < n_edges) {
        atomicAdd(&out[(size_t)dst[e] * OUT_F + c],
                  __half2float(tmp[(size_t)src[e] * OUT_F + c]));
    }
}

__global__ void finalize_kernel(float* __restrict__ out, const int* __restrict__ in_cnt,
                                int n_total) {
    int t = blockIdx.x * blockDim.x + threadIdx.x;
    if (t < n_total) {
        out[t] *= rsqrtf(fmaxf((float)in_cnt[t >> 5], 1.0f));
    }
}

extern "C" void kernel_launch(void* const* d_in, const int* in_sizes, int n_in,
                              void* d_out, int out_size, void* d_ws, size_t ws_size,
                              hipStream_t stream) {
    const float* feat   = (const float*)d_in[0];
    const int*   src    = (const int*)d_in[1];
    const int*   dst    = (const int*)d_in[2];
    const float* weight = (const float*)d_in[3];
    float*       out    = (float*)d_out;

    int n_nodes = in_sizes[0] / IN_F;   // 100000
    int n_edges = in_sizes[1];          // 1600000
    int n_buckets = (n_nodes + R_NODES - 1) / R_NODES;  // 391
    int n_bbl = (n_edges + EPB - 1) / EPB;              // 196
    int n_lbl = (n_nodes + 255) / 256;                  // 391

    // ws layout: [out_cnt n][in_cnt n][ovf_cnt 8][ovf 2*CAP]
    //            [cnts_d MAXNB*MAXBBL u16][cnts_s same]
    //            [bkt nb x n_bbl*C_D u32][bkt2 nb x n_bbl*C_S u8][tmp]
    int*      out_cnt = (int*)d_ws;
    int*      in_cnt  = out_cnt + n_nodes;
    int*      ovf_cnt = in_cnt + n_nodes;
    int*      ovf     = ovf_cnt + 8;
    unsigned short* cnts_d = (unsigned short*)(ovf + 2 * OVF_CAP);
    unsigned short* cnts_s = cnts_d + (size_t)MAXNB * MAXBBL;
    char*     bkt_raw = (char*)(cnts_s + (size_t)MAXNB * MAXBBL);
    unsigned* bkt     = (unsigned*)(((uintptr_t)bkt_raw + 15) & ~(uintptr_t)15);
    int sD = n_bbl * C_D;
    int sS = n_bbl * C_S;                   // bytes per src bucket
    unsigned char* bkt2 = (unsigned char*)(bkt + (size_t)n_buckets * sD);
    char*     tmp_raw = (char*)(bkt2 + (size_t)n_buckets * sS);
    __half*   tmp     = (__half*)(((uintptr_t)tmp_raw + 15) & ~(uintptr_t)15);
    size_t    needed  = (char*)(tmp + (size_t)n_nodes * OUT_F) - (char*)d_ws;

    if (ws_size >= needed && n_buckets <= MAXNB && n_bbl <= MAXBBL) {
        hipMemsetAsync(out_cnt, 0, ((size_t)2 * n_nodes + 8) * sizeof(int), stream);
        mega_kernel<<<n_bbl + n_lbl, 512, 0, stream>>>(
            src, dst, feat, weight, out_cnt, in_cnt, bkt, bkt2,
            cnts_d, cnts_s, ovf, ovf_cnt, tmp, n_edges, n_nodes, n_bbl, n_lbl);
        scale_tmp<<<n_buckets, 512, 0, stream>>>(
            bkt2, cnts_s, out_cnt, tmp, n_nodes, n_bbl);
        sortgather_kernel<<<n_buckets, 1024, 0, stream>>>(
            bkt, cnts_d, in_cnt, ovf, ovf_cnt, tmp, out, n_nodes, n_bbl);
    } else {
        // fallback: atomic scatter
        __half* tmp_fb = (__half*)(ovf + 2 * OVF_CAP);
        hipMemsetAsync(out_cnt, 0, ((size_t)2 * n_nodes + 8) * sizeof(int), stream);
        hipMemsetAsync(d_out, 0, (size_t)out_size * sizeof(float), stream);
        degree_kernel<<<(n_edges + 255) / 256, 256, 0, stream>>>(src, dst, out_cnt, in_cnt, n_edges);
        linear_fb<<<(n_nodes + 127) / 128, 256, 0, stream>>>(feat, weight, out_cnt, tmp_fb, n_nodes);
        long long st = (long long)n_edges * OUT_F;
        scatter_kernel<<<(int)((st + 255) / 256), 256, 0, stream>>>(src, dst, tmp_fb, out, n_edges);
        finalize_kernel<<<(n_nodes * OUT_F + 255) / 256, 256, 0, stream>>>(out, in_cnt, n_nodes * OUT_F);
    }
}